// Round 4
// baseline (892.463 us; speedup 1.0000x reference)
//
#include <hip/hip_runtime.h>
#include <stdint.h>
#include <math.h>

// ---------------------------------------------------------------- constants
#define DIM     1024
#define HID     4096
#define SEQ     2048
#define NB      4
#define NH      16
#define HD      64
#define NCHUNK  32          // SEQ / 64
#define MROWS   8192        // NB * SEQ
#define QSTR    3072        // fused qkv row stride

typedef unsigned short ushort_t;
typedef __attribute__((ext_vector_type(8))) short bf16x8;
typedef __attribute__((ext_vector_type(4))) float f32x4;

// ws layout (bytes) — peak ~193.5 MB, proven non-faulting
#define OFF_H    ((size_t)0)            // bf16 [8192][1024]
#define OFF_Q    ((size_t)16777216)     // bf16 [8192][3072] fused qkv
#define OFF_P    ((size_t)67108864)     // f32 [64][32][4096]
#define OFF_KS   ((size_t)100663296)    // f32 [64][32][64]
#define OFF_X1   ((size_t)101187584)    // f32 [8192][1024]
#define OFF_WQT  ((size_t)134742016)    // bf16 [3072][1024] fused qkv weights^T
#define OFF_WOT  ((size_t)141033472)
#define OFF_W1T  ((size_t)143130624)    // 3 x bf16 [4096][1024]
#define OFF_W2T  ((size_t)168296448)    // 3 x bf16 [1024][4096]
#define OFF_HIDB OFF_Q + 16777216       // bf16 [8192][4096]: spans old K,V,P (dead at CMS time)

__device__ __forceinline__ float b2f(ushort_t u) {
    return __uint_as_float(((unsigned int)u) << 16);
}
__device__ __forceinline__ ushort_t f2b(float f) {
    unsigned int u = __float_as_uint(f);
    u += 0x7FFFu + ((u >> 16) & 1u);          // round-to-nearest-even
    return (ushort_t)(u >> 16);
}
__device__ __forceinline__ void unpack4(uint2 u, float* f) {
    f[0] = __uint_as_float(u.x << 16);
    f[1] = __uint_as_float(u.x & 0xffff0000u);
    f[2] = __uint_as_float(u.y << 16);
    f[3] = __uint_as_float(u.y & 0xffff0000u);
}
// gelu(tanh form) == x*sigmoid(2z); ~7 VALU ops vs ~40 for libm tanhf
__device__ __forceinline__ float fast_gelu(float x) {
    const float u = x * (1.5957691216057308f + 0.07135481627f * x * x);  // 2z
    const float e = exp2f(-1.4426950408889634f * u);
    return x * __builtin_amdgcn_rcpf(1.0f + e);
}
__device__ __forceinline__ float fast_elu1(float x) {
    return x > 0.0f ? x + 1.0f : exp2f(1.4426950408889634f * x);
}
// async 16B global->LDS DMA; LDS dest must be wave-uniform base + lane*16 [m97/m104]
__device__ __forceinline__ void ldg16(const ushort_t* g, ushort_t* l) {
    __builtin_amdgcn_global_load_lds(
        (const __attribute__((address_space(1))) void*)g,
        (__attribute__((address_space(3))) void*)l, 16, 0, 0);
}

// ---------------------------------------------------------------- transpose (f32 -> bf16)
__global__ void __launch_bounds__(256)
transpose_f32_bf16(const float* __restrict__ src, ushort_t* __restrict__ dst, int R, int C)
{
    __shared__ float t[32][33];
    const int bx = blockIdx.x * 32;
    const int by = blockIdx.y * 32;
    const int tx = threadIdx.x, ty = threadIdx.y;
    #pragma unroll
    for (int i = ty; i < 32; i += 8)
        t[i][tx] = src[(size_t)(by + i) * C + bx + tx];
    __syncthreads();
    #pragma unroll
    for (int i = ty; i < 32; i += 8)
        dst[(size_t)(bx + i) * R + by + tx] = f2b(t[tx][i]);
}

// ---------------------------------------------------------------- layernorm (f32 in, bf16 out)
__global__ void __launch_bounds__(256)
ln_fwd(const float* __restrict__ xin, const float* __restrict__ g,
       const float* __restrict__ be, ushort_t* __restrict__ out)
{
    const int row = blockIdx.x, tid = threadIdx.x;
    const float4 f = ((const float4*)(xin + (size_t)row * DIM))[tid];
    float v[4] = {f.x, f.y, f.z, f.w};
    float s  = v[0] + v[1] + v[2] + v[3];
    float ss = v[0]*v[0] + v[1]*v[1] + v[2]*v[2] + v[3]*v[3];
    #pragma unroll
    for (int off = 32; off; off >>= 1) {
        s  += __shfl_down(s, off);
        ss += __shfl_down(ss, off);
    }
    __shared__ float red[2][4];
    const int wave = tid >> 6, lane = tid & 63;
    if (lane == 0) { red[0][wave] = s; red[1][wave] = ss; }
    __syncthreads();
    s  = red[0][0] + red[0][1] + red[0][2] + red[0][3];
    ss = red[1][0] + red[1][1] + red[1][2] + red[1][3];
    const float mean = s * (1.0f / DIM);
    const float var  = ss * (1.0f / DIM) - mean * mean;
    const float rstd = rsqrtf(var + 1e-5f);
    ushort_t o[4];
    #pragma unroll
    for (int i = 0; i < 4; i++) {
        const int col = tid * 4 + i;
        o[i] = f2b((v[i] - mean) * rstd * g[col] + be[col]);
    }
    uint2 u2;
    u2.x = (unsigned int)o[0] | ((unsigned int)o[1] << 16);
    u2.y = (unsigned int)o[2] | ((unsigned int)o[3] << 16);
    *(uint2*)(out + (size_t)row * DIM + tid * 4) = u2;
}

#define ACT_NONE 0
#define ACT_ELU1 1
#define ACT_GELU 2
#define ACT_QKV  3   // cols < 2048 -> elu+1 (Q,K); cols >= 2048 -> none (V). block-uniform.

// ---------------------------------------------------------------- GEMM 256x{256,128}, deep-prefetch 4-phase
// BM=256, BK=64, 512 threads = 8 waves (2M x 4N), double-buffered LDS, raw
// s_barrier only (no vmcnt(0) drain in loop), setprio(1) around MFMA clusters.
//
// Swizzle (round-1, verified conflict-free): LDS[(r,c)] = G[(r, c ^ ((r&7)<<4))].
// global_load_lds dest LINEAR; swizzle on the global source addr + ds_read addr.
//
// Deep prefetch (round-2): fragment regs persist across phases, so each 64-row
// LDS region is ds_read in exactly ONE phase; the phase's closing barrier
// proves all waves' reads completed. Tile t+2 shares tile t's buffer, and its
// regions die mid-tile -> stage t+2 DURING tile t:
//   deaths: A[0-63],A[128-191],Bf0(,Bf1 @BN256): ph0; Bf2,Bf3: ph1;
//           A[64-127],A[192-255]: ph2.   (BN128: Bf1 dies ph1)
//   stages: ph1: A0,A128,B0 | ph2: B64(,B128,B192) | ph3: A64,A192.
// Boundary wait = vmcnt(LPT): tile t+1 landed (staged a full tile earlier,
// 4-7 phases of slack ~2500-4300cy >> HBM latency), tile t+2's LPT in flight.
// B col-frag mapping: frag f <-> B rows f*64 + wn*16 + m (contiguous 8KB
// stage regions); output col = bn + f*64 + wn*16 + ccol.
//
// Round-3 audit (container failed, no counters): uniform control flow (no
// barrier divergence), staged tile index <= NT-1, all staged rows in-bounds,
// max 2*LPT=16 outstanding vmem (<63), region lifetimes race-free under
// "memory"-clobbered waitcnts + sched_barrier(0) [rule 18]. Resubmitted as-is.

#define G_RD_A(BUF, FR0) \
    _Pragma("unroll") for (int _i = 0; _i < 4; ++_i) \
    _Pragma("unroll") for (int _kk = 0; _kk < 2; ++_kk) \
        af[_i][_kk] = *(const bf16x8*)(ldsb + (BUF) + aoff + (((FR0) + _i) << 11) \
                                       + (((_kk << 6) | qv16) ^ mflip))

#define G_RD_B(BUF, F) \
    _Pragma("unroll") for (int _kk = 0; _kk < 2; ++_kk) \
        bf[(F)][_kk] = *(const bf16x8*)(ldsb + (BUF) + boff + ((F) << 13) \
                                        + (((_kk << 6) | qv16) ^ mflip))

#define G_MFMA(AR, C0, CNT) \
    _Pragma("unroll") for (int _i = 0; _i < 4; ++_i) \
    _Pragma("unroll") for (int _c = 0; _c < (CNT); ++_c) \
    _Pragma("unroll") for (int _kk = 0; _kk < 2; ++_kk) \
        acc[(AR) + _i][(C0) + _c] = __builtin_amdgcn_mfma_f32_16x16x32_bf16( \
            af[_i][_kk], bf[(C0) + _c][_kk], acc[(AR) + _i][(C0) + _c], 0, 0, 0)

// stage one 64-row region (8KB, 1 ldg16/thread) of A / B of tile T
#define ST_A(BUFO, T, R) ldg16(pA + (size_t)(R) * K + (size_t)(T) * 64, \
    (ushort_t*)(ldsb + (BUFO) + ((R) << 7) + (tid << 4)))
#define ST_B(BUFO, T, R) ldg16(pB + (size_t)(R) * K + (size_t)(T) * 64, \
    (ushort_t*)(ldsb + (BUFO) + 32768 + ((R) << 7) + (tid << 4)))

#define G_BARW() do { \
    __builtin_amdgcn_s_barrier(); \
    asm volatile("s_waitcnt lgkmcnt(0)" ::: "memory"); \
    __builtin_amdgcn_sched_barrier(0); \
    __builtin_amdgcn_s_setprio(1); \
} while (0)

#define G_ENDP() do { \
    __builtin_amdgcn_s_setprio(0); \
    __builtin_amdgcn_s_barrier(); \
} while (0)

// one K-tile: 4 phases; stages tile TS (same buffer) when `more`
#define G_TILE(BUFO, TS) do { \
    /* ph0 */ \
    G_RD_A(BUFO, 0); \
    _Pragma("unroll") for (int _f = 0; _f < NF / 2; ++_f) G_RD_B(BUFO, _f); \
    G_BARW(); G_MFMA(0, 0, NF / 2); G_ENDP(); \
    /* ph1 */ \
    _Pragma("unroll") for (int _f = NF / 2; _f < NF; ++_f) G_RD_B(BUFO, _f); \
    if (more) { ST_A(BUFO, TS, 0); ST_A(BUFO, TS, 128); ST_B(BUFO, TS, 0); } \
    G_BARW(); G_MFMA(0, NF / 2, NF / 2); G_ENDP(); \
    /* ph2 */ \
    G_RD_A(BUFO, 4); \
    if (more) { \
        ST_B(BUFO, TS, 64); \
        if constexpr (NF == 4) { ST_B(BUFO, TS, 128); ST_B(BUFO, TS, 192); } \
    } \
    G_BARW(); G_MFMA(4, 0, NF / 2); G_ENDP(); \
    /* ph3 */ \
    if (more) { ST_A(BUFO, TS, 64); ST_A(BUFO, TS, 192); } \
    G_BARW(); G_MFMA(4, NF / 2, NF / 2); \
    __builtin_amdgcn_s_setprio(0); \
    if (more) asm volatile("s_waitcnt vmcnt(%0)" :: "i"(LPT) : "memory"); \
    else      asm volatile("s_waitcnt vmcnt(0)" ::: "memory"); \
    __builtin_amdgcn_s_barrier(); \
} while (0)

template<int BN_, int ACT, bool BIAS, bool RES, bool OUTF32>
__global__ void __launch_bounds__(512, 2)
gemm256(const ushort_t* __restrict__ A, const ushort_t* __restrict__ Bt,
        const float* __restrict__ bias, const float* __restrict__ resid,
        void* __restrict__ Cout, int M, int N, int K)
{
    constexpr int NF    = BN_ / 64;              // col-frags per wave (4 or 2)
    constexpr int BUFSZ = 32768 + BN_ * 128;     // A 32KB + B BN*64*2B per buffer
    constexpr int LPT   = 4 + NF;                // ldg16 per thread per K-tile
    __shared__ __align__(16) char ldsb[2 * BUFSZ];

    const int tid  = threadIdx.x;
    const int lane = tid & 63, wave = tid >> 6;
    const int wm_idx = wave >> 2, wn_idx = wave & 3;
    const int bm = blockIdx.x * 256, bn = blockIdx.y * BN_;

    // staging: thread covers row base+r0, 16B at pre-swizzled col
    const int r0  = tid >> 3;
    const int kbs = (((tid & 7) ^ (r0 & 7)) << 4);          // byte col, inverse-swizzled
    const ushort_t* pA = A  + (size_t)(bm + r0) * K + (kbs >> 1);
    const ushort_t* pB = Bt + (size_t)(bn + r0) * K + (kbs >> 1);

    // fragment reads
    const int m     = lane & 15;
    const int qv16  = (lane >> 4) << 4;          // 0,16,32,48 bytes
    const int mflip = (m & 7) << 4;              // swizzle on read
    const int aoff  = (wm_idx * 128 + m) << 7;
    const int boff  = 32768 + ((wn_idx * 16 + m) << 7);

    f32x4  acc[8][NF] = {};
    bf16x8 af[4][2], bf[NF][2];

    const int NT    = K >> 6;                    // K % 128 == 0 -> NT even
    const int niter = NT >> 1;

    // prologue: stage tiles 0 and 1 fully; wait tile0 landed (tile1 may fly)
    ST_A(0, 0, 0); ST_A(0, 0, 64); ST_A(0, 0, 128); ST_A(0, 0, 192);
    ST_B(0, 0, 0); ST_B(0, 0, 64);
    if constexpr (NF == 4) { ST_B(0, 0, 128); ST_B(0, 0, 192); }
    ST_A(BUFSZ, 1, 0); ST_A(BUFSZ, 1, 64); ST_A(BUFSZ, 1, 128); ST_A(BUFSZ, 1, 192);
    ST_B(BUFSZ, 1, 0); ST_B(BUFSZ, 1, 64);
    if constexpr (NF == 4) { ST_B(BUFSZ, 1, 128); ST_B(BUFSZ, 1, 192); }
    asm volatile("s_waitcnt vmcnt(%0)" :: "i"(LPT) : "memory");
    __builtin_amdgcn_s_barrier();

    for (int it = 0; it < niter; ++it) {
        const int  t    = it << 1;
        const bool more = (it + 1) < niter;
        G_TILE(0,     t + 2);                    // even tile -> buf0, stage t+2
        G_TILE(BUFSZ, t + 3);                    // odd  tile -> buf1, stage t+3
    }

    // epilogue: C/D layout col=lane&15, row=(lane>>4)*4+reg [m89/m91]
    const int cr   = (lane >> 4) << 2;
    const int ccol = lane & 15;
    #pragma unroll
    for (int fr = 0; fr < 8; ++fr) {
        #pragma unroll
        for (int fc = 0; fc < NF; ++fc) {
            const int gc = bn + fc * 64 + wn_idx * 16 + ccol;
            const float bv = BIAS ? bias[gc] : 0.0f;
            #pragma unroll
            for (int j = 0; j < 4; ++j) {
                const int gr = bm + wm_idx * 128 + fr * 16 + cr + j;
                float vv = acc[fr][fc][j] + bv;
                if (ACT == ACT_ELU1) vv = fast_elu1(vv);
                if (ACT == ACT_GELU) vv = fast_gelu(vv);
                if (ACT == ACT_QKV)  vv = (bn < 2048) ? fast_elu1(vv) : vv;
                const size_t oidx = (size_t)gr * N + gc;
                if (RES) vv += resid[oidx];
                if (OUTF32) ((float*)Cout)[oidx] = vv;
                else        ((ushort_t*)Cout)[oidx] = f2b(vv);
            }
        }
    }
    (void)M;
}

// ---------------------------------------------------------------- attention
// qkv buffer row stride = QSTR; K at col 1024, V at col 2048
__global__ void __launch_bounds__(256)
attn_phase1(const ushort_t* __restrict__ qkv,
            float* __restrict__ P, float* __restrict__ Ksum)
{
    const int c = blockIdx.x, h = blockIdx.y, b = blockIdx.z;
    __shared__ ushort_t Ks[64][68], Vs[64][68];
    const int tid = threadIdx.x;
    const size_t rowbase = (size_t)b * SEQ + c * 64;
    #pragma unroll
    for (int i = 0; i < 4; i++) {
        const int lin = tid + 256 * i;          // (t, d4) over 64x16
        const int t = lin >> 4, d4 = (lin & 15) * 4;
        const size_t gidx = (rowbase + t) * QSTR + h * HD + d4;
        *(uint2*)&Ks[t][d4] = *(const uint2*)(qkv + 1024 + gidx);
        *(uint2*)&Vs[t][d4] = *(const uint2*)(qkv + 2048 + gidx);
    }
    __syncthreads();
    const int d0 = (tid >> 4) * 4, e0 = (tid & 15) * 4;
    float acc[4][4] = {};
    for (int t = 0; t < 64; t++) {
        float kf[4], vf[4];
        unpack4(*(const uint2*)&Ks[t][d0], kf);
        unpack4(*(const uint2*)&Vs[t][e0], vf);
        #pragma unroll
        for (int i = 0; i < 4; i++)
            #pragma unroll
            for (int j = 0; j < 4; j++)
                acc[i][j] += kf[i] * vf[j];
    }
    const size_t pbase = (((size_t)b * NH + h) * NCHUNK + c) * 4096;
    #pragma unroll
    for (int i = 0; i < 4; i++) {
        float4 o; o.x = acc[i][0]; o.y = acc[i][1]; o.z = acc[i][2]; o.w = acc[i][3];
        *(float4*)(P + pbase + (size_t)(d0 + i) * 64 + e0) = o;
    }
    if (tid < 64) {
        float a = 0.0f;
        for (int t = 0; t < 64; t++) a += b2f(Ks[t][tid]);
        Ksum[(((size_t)b * NH + h) * NCHUNK + c) * 64 + tid] = a;
    }
}

// phase 1b: exclusive prefix over chunks, column-parallel.
__global__ void __launch_bounds__(256)
attn_prefix(float* __restrict__ P, float* __restrict__ Ksum)
{
    const int bh = blockIdx.y;
    const int e  = blockIdx.x * 256 + threadIdx.x;
    const size_t base = (size_t)bh * NCHUNK * 4096 + e;
    float acc = 0.0f;
    #pragma unroll
    for (int c = 0; c < NCHUNK; c++) {
        const float t = P[base + (size_t)c * 4096];
        P[base + (size_t)c * 4096] = acc;
        acc += t;
    }
    if (blockIdx.x == 0 && threadIdx.x < 64) {
        const size_t kb = (size_t)bh * NCHUNK * 64 + threadIdx.x;
        float a = 0.0f;
        #pragma unroll
        for (int c = 0; c < NCHUNK; c++) {
            const float t = Ksum[kb + c * 64];
            Ksum[kb + c * 64] = a;
            a += t;
        }
    }
}

// phase 2: out = (Q@M_prev + causal(QK^T)@V) / (Q@ksum_prev + rowsum(S) + 1e-6)
__global__ void __launch_bounds__(256)
attn_phase2(const ushort_t* __restrict__ qkv, const float* __restrict__ P,
            const float* __restrict__ Ksum, ushort_t* __restrict__ Out)
{
    const int c = blockIdx.x, h = blockIdx.y, b = blockIdx.z;
    const int tid = threadIdx.x;
    __shared__ ushort_t Qs[64][68], KsB[64][68], VsB[64][68];
    __shared__ float S[64][68];
    __shared__ float Mp[64][64];
    __shared__ float kp[64];
    __shared__ float partial[4][64];
    const size_t rowbase = (size_t)b * SEQ + c * 64;
    const size_t pbase = (((size_t)b * NH + h) * NCHUNK + c) * 4096;
    #pragma unroll
    for (int i = 0; i < 4; i++) {
        const int lin = tid + 256 * i;          // (t, d4) over 64x16
        const int t = lin >> 4, d4 = (lin & 15) * 4;
        const size_t gidx = (rowbase + t) * QSTR + h * HD + d4;
        *(uint2*)&Qs[t][d4]  = *(const uint2*)(qkv + gidx);
        *(uint2*)&KsB[t][d4] = *(const uint2*)(qkv + 1024 + gidx);
        *(uint2*)&VsB[t][d4] = *(const uint2*)(qkv + 2048 + gidx);
        *(float4*)&Mp[t][d4] = *(const float4*)(P + pbase + lin * 4);
    }
    if (tid < 64) kp[tid] = Ksum[(((size_t)b * NH + h) * NCHUNK + c) * 64 + tid];
    __syncthreads();

    const int t0 = (tid >> 4) * 4;
    const int c0 = (tid & 15) * 4;              // ii-block for S phase, e-block later

    // S = causal(Q K^T); masked entries written as 0
    {
        float accS[4][4] = {};
        for (int d4 = 0; d4 < 64; d4 += 4) {
            float qf[4][4], kf[4][4];
            #pragma unroll
            for (int i = 0; i < 4; i++) {
                unpack4(*(const uint2*)&Qs[t0 + i][d4], qf[i]);
                unpack4(*(const uint2*)&KsB[c0 + i][d4], kf[i]);
            }
            #pragma unroll
            for (int i = 0; i < 4; i++)
                #pragma unroll
                for (int j = 0; j < 4; j++)
                    #pragma unroll
                    for (int dd = 0; dd < 4; dd++)
                        accS[i][j] += qf[i][dd] * kf[j][dd];
        }
        #pragma unroll
        for (int i = 0; i < 4; i++) {
            float4 sv;
            sv.x = (c0 + 0 <= t0 + i) ? accS[i][0] : 0.0f;
            sv.y = (c0 + 1 <= t0 + i) ? accS[i][1] : 0.0f;
            sv.z = (c0 + 2 <= t0 + i) ? accS[i][2] : 0.0f;
            sv.w = (c0 + 3 <= t0 + i) ? accS[i][3] : 0.0f;
            *(float4*)&S[t0 + i][c0] = sv;
        }
    }
    __syncthreads();

    // den partials: quarter-range per thread
    {
        const int t = tid & 63, q = tid >> 6;
        const int base = q * 16;
        float a = 0.0f;
        #pragma unroll
        for (int ii = 0; ii < 16; ii++) a += S[t][base + ii];
        #pragma unroll
        for (int d = 0; d < 16; d++) a += b2f(Qs[t][base + d]) * kp[base + d];
        partial[q][t] = a;
    }
    __syncthreads();

    // out = S@V + Q@Mp, then /den
    float acc[4][4] = {};
    for (int ii = 0; ii < 64; ii++) {
        float vf[4];
        unpack4(*(const uint2*)&VsB[ii][c0], vf);
        #pragma unroll
        for (int i = 0; i < 4; i++) {
            const float s = S[t0 + i][ii];
            #pragma unroll
            for (int j = 0; j < 4; j++) acc[i][j] += s * vf[j];
        }
    }
    for (int d = 0; d < 64; d++) {
        const float4 mp = *(const float4*)&Mp[d][c0];
        #pragma unroll
        for (int i = 0; i < 4; i++) {
            const float qv = b2f(Qs[t0 + i][d]);
            acc[i][0] += qv * mp.x; acc[i][1] += qv * mp.y;
            acc[i][2] += qv * mp.z; acc[i][3] += qv * mp.w;
        }
    }
    #pragma unroll
    for (int i = 0; i < 4; i++) {
        const float dent = partial[0][t0 + i] + partial[1][t0 + i] +
                           partial[2][t0 + i] + partial[3][t0 + i] + 1e-6f;
        const float r = 1.0f / dent;
        ushort_t o[4];
        #pragma unroll
        for (int j = 0; j < 4; j++) o[j] = f2b(acc[i][j] * r);
        uint2 u2;
        u2.x = (unsigned int)o[0] | ((unsigned int)o[1] << 16);
        u2.y = (unsigned int)o[2] | ((unsigned int)o[3] << 16);
        *(uint2*)(Out + (rowbase + t0 + i) * DIM + h * HD + c0) = u2;
    }
}

// ---------------------------------------------------------------- launcher
extern "C" void kernel_launch(void* const* d_in, const int* in_sizes, int n_in,
                              void* d_out, int out_size, void* d_ws, size_t ws_size,
                              hipStream_t stream)
{
    const float* x      = (const float*)d_in[0];
    const float* Wq     = (const float*)d_in[1];
    const float* Wk     = (const float*)d_in[2];
    const float* Wv     = (const float*)d_in[3];
    const float* Wo     = (const float*)d_in[4];
    const float* ln1g   = (const float*)d_in[5];
    const float* ln1b   = (const float*)d_in[6];
    const float* ln2g   = (const float*)d_in[7];
    const float* ln2b   = (const float*)d_in[8];
    const float* cw1    = (const float*)d_in[9];
    const float* cb1    = (const float*)d_in[10];
    const float* cw2    = (const float*)d_in[11];
    const float* cb2    = (const float*)d_in[12];

    char* ws = (char*)d_ws;
    ushort_t* h     = (ushort_t*)(ws + OFF_H);
    ushort_t* qkv   = (ushort_t*)(ws + OFF_Q);
    float*    Pb    = (float*)(ws + OFF_P);
    float*    ksb   = (float*)(ws + OFF_KS);
    float*    x1    = (float*)(ws + OFF_X1);
    ushort_t* wqkvt = (ushort_t*)(ws + OFF_WQT);
    ushort_t* wot   = (ushort_t*)(ws + OFF_WOT);
    ushort_t* w1t   = (ushort_t*)(ws + OFF_W1T);
    ushort_t* w2t   = (ushort_t*)(ws + OFF_W2T);
    ushort_t* hid   = (ushort_t*)(ws + OFF_HIDB);
    float*    outp  = (float*)d_out;

    const dim3 tb(32, 8);
    // fused qkv weight^T: [3072][1024]
    transpose_f32_bf16<<<dim3(32, 32), tb, 0, stream>>>(Wq, wqkvt,                   DIM, DIM);
    transpose_f32_bf16<<<dim3(32, 32), tb, 0, stream>>>(Wk, wqkvt + 1024 * 1024,     DIM, DIM);
    transpose_f32_bf16<<<dim3(32, 32), tb, 0, stream>>>(Wv, wqkvt + 2 * 1024 * 1024, DIM, DIM);
    transpose_f32_bf16<<<dim3(32, 32), tb, 0, stream>>>(Wo, wot, DIM, DIM);
    for (int l = 0; l < 3; l++) {
        transpose_f32_bf16<<<dim3(128, 32), tb, 0, stream>>>(cw1 + (size_t)l * DIM * HID,
                                                             w1t + (size_t)l * HID * DIM, DIM, HID);
        transpose_f32_bf16<<<dim3(32, 128), tb, 0, stream>>>(cw2 + (size_t)l * HID * DIM,
                                                             w2t + (size_t)l * DIM * HID, HID, DIM);
    }

    ln_fwd<<<MROWS, 256, 0, stream>>>(x, ln1g, ln1b, h);

    // fused Q|K|V projection: [8192][3072], elu+1 on first 2048 cols
    // BN=128 -> 32x24 = 768 wg = 3 full waves of 256 CUs
    gemm256<128, ACT_QKV, false, false, false><<<dim3(32, 24), 512, 0, stream>>>(
        h, wqkvt, nullptr, nullptr, qkv, MROWS, QSTR, DIM);

    attn_phase1<<<dim3(NCHUNK, NH, NB), 256, 0, stream>>>(qkv, Pb, ksb);
    attn_prefix<<<dim3(16, 64), 256, 0, stream>>>(Pb, ksb);
    attn_phase2<<<dim3(NCHUNK, NH, NB), 256, 0, stream>>>(qkv, Pb, ksb, h);  // h := attn out

    // Wo: N=1024, BN=128 -> 32x8 = 256 wg (exact fill)
    gemm256<128, ACT_NONE, false, true, true><<<dim3(32, 8), 512, 0, stream>>>(
        h, wot, nullptr, x, x1, MROWS, DIM, DIM);

    ln_fwd<<<MROWS, 256, 0, stream>>>(x1, ln2g, ln2b, h);

    const ushort_t* cur = h;
    for (int l = 0; l < 3; l++) {
        // w1: N=4096, BN=256 -> 32x16 = 512 wg = 2 full waves
        gemm256<256, ACT_GELU, true, false, false><<<dim3(32, 16), 512, 0, stream>>>(
            cur, w1t + (size_t)l * HID * DIM, cb1 + (size_t)l * HID, nullptr, hid, MROWS, HID, DIM);
        if (l < 2) {
            // w2: N=1024 K=4096, BN=128 -> 256 wg (exact fill)
            gemm256<128, ACT_NONE, true, false, false><<<dim3(32, 8), 512, 0, stream>>>(
                hid, w2t + (size_t)l * DIM * HID, cb2 + (size_t)l * DIM, nullptr, h, MROWS, DIM, HID);
            cur = h;
        } else {
            gemm256<128, ACT_NONE, true, true, true><<<dim3(32, 8), 512, 0, stream>>>(
                hid, w2t + (size_t)l * DIM * HID, cb2 + (size_t)l * DIM, x1, outp, MROWS, DIM, HID);
        }
    }
    (void)in_sizes; (void)n_in; (void)out_size; (void)ws_size;
}

// Round 5
// 866.090 us; speedup vs baseline: 1.0305x; 1.0305x over previous
//
#include <hip/hip_runtime.h>
#include <stdint.h>
#include <math.h>

// ---------------------------------------------------------------- constants
#define DIM     1024
#define HID     4096
#define SEQ     2048
#define NB      4
#define NH      16
#define HD      64
#define NCHUNK  32          // SEQ / 64
#define MROWS   8192        // NB * SEQ
#define QSTR    3072        // fused qkv row stride

typedef unsigned short ushort_t;
typedef __attribute__((ext_vector_type(8))) short bf16x8;
typedef __attribute__((ext_vector_type(4))) float f32x4;

// ws layout (bytes) — peak ~193.5 MB, proven non-faulting
#define OFF_H    ((size_t)0)            // bf16 [8192][1024]
#define OFF_Q    ((size_t)16777216)     // bf16 [8192][3072] fused qkv
#define OFF_P    ((size_t)67108864)     // f32 [64][32][4096]
#define OFF_KS   ((size_t)100663296)    // f32 [64][32][64]
#define OFF_X1   ((size_t)101187584)    // f32 [8192][1024]
#define OFF_WQT  ((size_t)134742016)    // bf16 [3072][1024] fused qkv weights^T
#define OFF_WOT  ((size_t)141033472)
#define OFF_W1T  ((size_t)143130624)    // 3 x bf16 [4096][1024]
#define OFF_W2T  ((size_t)168296448)    // 3 x bf16 [1024][4096]
#define OFF_HIDB OFF_Q + 16777216       // bf16 [8192][4096]: spans old K,V,P (dead at CMS time)

__device__ __forceinline__ float b2f(ushort_t u) {
    return __uint_as_float(((unsigned int)u) << 16);
}
__device__ __forceinline__ ushort_t f2b(float f) {
    unsigned int u = __float_as_uint(f);
    u += 0x7FFFu + ((u >> 16) & 1u);          // round-to-nearest-even
    return (ushort_t)(u >> 16);
}
__device__ __forceinline__ void unpack4(uint2 u, float* f) {
    f[0] = __uint_as_float(u.x << 16);
    f[1] = __uint_as_float(u.x & 0xffff0000u);
    f[2] = __uint_as_float(u.y << 16);
    f[3] = __uint_as_float(u.y & 0xffff0000u);
}
// gelu(tanh form) == x*sigmoid(2z); ~7 VALU ops vs ~40 for libm tanhf
__device__ __forceinline__ float fast_gelu(float x) {
    const float u = x * (1.5957691216057308f + 0.07135481627f * x * x);  // 2z
    const float e = exp2f(-1.4426950408889634f * u);
    return x * __builtin_amdgcn_rcpf(1.0f + e);
}
__device__ __forceinline__ float fast_elu1(float x) {
    return x > 0.0f ? x + 1.0f : exp2f(1.4426950408889634f * x);
}
// async 16B global->LDS DMA; LDS dest must be wave-uniform base + lane*16 [m97/m104]
__device__ __forceinline__ void ldg16(const ushort_t* g, ushort_t* l) {
    __builtin_amdgcn_global_load_lds(
        (const __attribute__((address_space(1))) void*)g,
        (__attribute__((address_space(3))) void*)l, 16, 0, 0);
}

// ---------------------------------------------------------------- transpose (f32 -> bf16)
__global__ void __launch_bounds__(256)
transpose_f32_bf16(const float* __restrict__ src, ushort_t* __restrict__ dst, int R, int C)
{
    __shared__ float t[32][33];
    const int bx = blockIdx.x * 32;
    const int by = blockIdx.y * 32;
    const int tx = threadIdx.x, ty = threadIdx.y;
    #pragma unroll
    for (int i = ty; i < 32; i += 8)
        t[i][tx] = src[(size_t)(by + i) * C + bx + tx];
    __syncthreads();
    #pragma unroll
    for (int i = ty; i < 32; i += 8)
        dst[(size_t)(bx + i) * R + by + tx] = f2b(t[tx][i]);
}

// ---------------------------------------------------------------- layernorm (f32 in, bf16 out)
__global__ void __launch_bounds__(256)
ln_fwd(const float* __restrict__ xin, const float* __restrict__ g,
       const float* __restrict__ be, ushort_t* __restrict__ out)
{
    const int row = blockIdx.x, tid = threadIdx.x;
    const float4 f = ((const float4*)(xin + (size_t)row * DIM))[tid];
    float v[4] = {f.x, f.y, f.z, f.w};
    float s  = v[0] + v[1] + v[2] + v[3];
    float ss = v[0]*v[0] + v[1]*v[1] + v[2]*v[2] + v[3]*v[3];
    #pragma unroll
    for (int off = 32; off; off >>= 1) {
        s  += __shfl_down(s, off);
        ss += __shfl_down(ss, off);
    }
    __shared__ float red[2][4];
    const int wave = tid >> 6, lane = tid & 63;
    if (lane == 0) { red[0][wave] = s; red[1][wave] = ss; }
    __syncthreads();
    s  = red[0][0] + red[0][1] + red[0][2] + red[0][3];
    ss = red[1][0] + red[1][1] + red[1][2] + red[1][3];
    const float mean = s * (1.0f / DIM);
    const float var  = ss * (1.0f / DIM) - mean * mean;
    const float rstd = rsqrtf(var + 1e-5f);
    ushort_t o[4];
    #pragma unroll
    for (int i = 0; i < 4; i++) {
        const int col = tid * 4 + i;
        o[i] = f2b((v[i] - mean) * rstd * g[col] + be[col]);
    }
    uint2 u2;
    u2.x = (unsigned int)o[0] | ((unsigned int)o[1] << 16);
    u2.y = (unsigned int)o[2] | ((unsigned int)o[3] << 16);
    *(uint2*)(out + (size_t)row * DIM + tid * 4) = u2;
}

#define ACT_NONE 0
#define ACT_ELU1 1
#define ACT_GELU 2
#define ACT_QKV  3   // cols < 2048 -> elu+1 (Q,K); cols >= 2048 -> none (V). block-uniform.

// ---------------------------------------------------------------- GEMM 256x128, ds-read-pipelined 4-phase
// BM=256, BK=64, 512 threads = 8 waves (2M x 4N), double-buffered LDS.
//
// Round-4 post-mortem: per K-tile, MFMA issue = ~2483 cy/SIMD but measured
// 6450 cy -> LDS delivery and MFMA were SERIALIZED: each phase's ds_reads
// were issued post-barrier and consumed immediately behind lgkmcnt(0).
// Round-5 fix: pipeline ds_reads ONE PHASE AHEAD into persistent reg sets
//   afl(rows 0-3) afh(rows 4-7) bfl(col-frags 0..NH2-1) bfh(NH2..NF-1):
//   ph3(t-1): rd afl,bfl(t) [cross-buffer]  |  ph0(t): rd bfh(t)
//   ph1(t):   rd afh(t)                     |  ph2(t): no reads
// Each phase's MFMA consumes data delivered during the PREVIOUS phase's
// MFMA. NO manual lgkmcnt: hipcc inserts minimal counted waits itself
// [m97: lgkmcnt(4/3/1/0)] — correctness never depends on my DS counts.
// ONE barrier per phase (closing); sched_barrier(0) after it pins issue
// points so reads can't sink/hoist across phases [rule 18 analog].
//
// Stage-after-read invariants (stage of region R issued >= 1 barrier after
// the phase whose MFMA forced delivery of R's readers):
//   A0,A128 (afl): delivered ph0 -> staged ph1.  B0-63 (bfl f0): ph0 -> ph1.
//   B64-127 (bfh f1): delivered ph1 -> staged ph2.
//   A64,A192 (afh): delivered ph2 -> staged ph3.
// vmcnt (in-order retire, m135): one per tile at ph2-end:
//   staging tiles: outstanding = this tile's 4 issued stages -> vmcnt(4)
//   guarantees ALL older loads (tile t+1's full set) landed before ph3's
//   cross-buffer reads.  Non-staging tail tiles: vmcnt(0).
// Swizzle (round-1, verified 0 conflicts): LDS[(r,c)] = G[(r, c^((r&7)<<4))],
// linear gload_lds dest + pre-swizzled global src + swizzled ds_read [rule 21].
// BN=128 everywhere: two A-reg-sets fit (≈184 regs); BN=256 would need ~284
// -> spill at the mandatory 2 waves/SIMD. BN128 overlapped ceiling ≈ 76%
// (LDS-bound: 1241 cy MFMA vs ~1600 cy LDS per K-tile).

#define RD_AF(DST, BUFO, FR0) \
    _Pragma("unroll") for (int _i = 0; _i < 4; ++_i) \
    _Pragma("unroll") for (int _kk = 0; _kk < 2; ++_kk) \
        DST[_i][_kk] = *(const bf16x8*)(ldsb + (BUFO) + aoff + (((FR0) + _i) << 11) \
                                        + (((_kk << 6) | qv16) ^ mflip))

#define RD_BF(DST, BUFO, F0) \
    _Pragma("unroll") for (int _c = 0; _c < NH2; ++_c) \
    _Pragma("unroll") for (int _kk = 0; _kk < 2; ++_kk) \
        DST[_c][_kk] = *(const bf16x8*)(ldsb + (BUFO) + boff + (((F0) + _c) << 13) \
                                        + (((_kk << 6) | qv16) ^ mflip))

#define G_MM(AR, C0, AF, BF) \
    _Pragma("unroll") for (int _i = 0; _i < 4; ++_i) \
    _Pragma("unroll") for (int _c = 0; _c < NH2; ++_c) \
    _Pragma("unroll") for (int _kk = 0; _kk < 2; ++_kk) \
        acc[(AR) + _i][(C0) + _c] = __builtin_amdgcn_mfma_f32_16x16x32_bf16( \
            AF[_i][_kk], BF[_c][_kk], acc[(AR) + _i][(C0) + _c], 0, 0, 0)

// stage one 64-row region (8KB, 1 ldg16/thread) of A / B of tile T
#define ST_A(BUFO, T, R) ldg16(pA + (size_t)(R) * K + (size_t)(T) * 64, \
    (ushort_t*)(ldsb + (BUFO) + ((R) << 7) + (tid << 4)))
#define ST_B(BUFO, T, R) ldg16(pB + (size_t)(R) * K + (size_t)(T) * 64, \
    (ushort_t*)(ldsb + (BUFO) + 32768 + ((R) << 7) + (tid << 4)))

// phase close: one barrier, then pin the scheduling region boundary
#define G_PHE() do { \
    __builtin_amdgcn_s_setprio(0); \
    __builtin_amdgcn_s_barrier(); \
    __builtin_amdgcn_sched_barrier(0); \
} while (0)

// one K-tile: 4 phases; reads pipelined one phase ahead; stages tile TS
// (same buffer) when MST; ph3 prefetch-reads next tile (NBUFO) when MRD.
#define G_TILE(BUFO, NBUFO, TS, MRD, MST) do { \
    /* ph0: rd bfh(cur); mfma afl x bfl */ \
    RD_BF(bfh, BUFO, NH2); \
    __builtin_amdgcn_s_setprio(1); G_MM(0, 0, afl, bfl); G_PHE(); \
    /* ph1: rd afh; stage A0,A128,B0; mfma afl x bfh */ \
    RD_AF(afh, BUFO, 4); \
    if (MST) { ST_A(BUFO, TS, 0); ST_A(BUFO, TS, 128); ST_B(BUFO, TS, 0); } \
    __builtin_amdgcn_s_setprio(1); G_MM(0, NH2, afl, bfh); G_PHE(); \
    /* ph2: stage B64; mfma afh x bfl; vmcnt before barrier */ \
    if (MST) { ST_B(BUFO, TS, 64); } \
    __builtin_amdgcn_s_setprio(1); G_MM(4, 0, afh, bfl); \
    __builtin_amdgcn_s_setprio(0); \
    if (MST) asm volatile("s_waitcnt vmcnt(%0)" :: "i"(VCT) : "memory"); \
    else     asm volatile("s_waitcnt vmcnt(0)" ::: "memory"); \
    __builtin_amdgcn_s_barrier(); \
    __builtin_amdgcn_sched_barrier(0); \
    /* ph3: rd afl,bfl(next tile, other buf); stage A64,A192; mfma afh x bfh */ \
    if (MRD) { RD_AF(afl, NBUFO, 0); RD_BF(bfl, NBUFO, 0); } \
    if (MST) { ST_A(BUFO, TS, 64); ST_A(BUFO, TS, 192); } \
    __builtin_amdgcn_s_setprio(1); G_MM(4, NH2, afh, bfh); G_PHE(); \
} while (0)

template<int BN_, int ACT, bool BIAS, bool RES, bool OUTF32>
__global__ void __launch_bounds__(512, 2)
gemm256(const ushort_t* __restrict__ A, const ushort_t* __restrict__ Bt,
        const float* __restrict__ bias, const float* __restrict__ resid,
        void* __restrict__ Cout, int M, int N, int K)
{
    constexpr int NF    = BN_ / 64;              // col-frags per wave (2 for BN128)
    constexpr int NH2   = NF / 2;                // col-frags per phase-half
    constexpr int BUFSZ = 32768 + BN_ * 128;     // A 32KB + B BN*64*2B per buffer
    constexpr int LPT   = 4 + NF;                // ldg16 per thread per K-tile
    constexpr int VCT   = 3 + (NF == 4 ? 3 : 1); // outstanding own-tile stages at ph2
    __shared__ __align__(16) char ldsb[2 * BUFSZ];

    const int tid  = threadIdx.x;
    const int lane = tid & 63, wave = tid >> 6;
    const int wm_idx = wave >> 2, wn_idx = wave & 3;
    const int bm = blockIdx.x * 256, bn = blockIdx.y * BN_;

    // staging: thread covers row base+r0, 16B at pre-swizzled col
    const int r0  = tid >> 3;
    const int kbs = (((tid & 7) ^ (r0 & 7)) << 4);          // byte col, inverse-swizzled
    const ushort_t* pA = A  + (size_t)(bm + r0) * K + (kbs >> 1);
    const ushort_t* pB = Bt + (size_t)(bn + r0) * K + (kbs >> 1);

    // fragment reads
    const int m     = lane & 15;
    const int qv16  = (lane >> 4) << 4;          // 0,16,32,48 bytes
    const int mflip = (m & 7) << 4;              // swizzle on read
    const int aoff  = (wm_idx * 128 + m) << 7;
    const int boff  = 32768 + ((wn_idx * 16 + m) << 7);

    f32x4  acc[8][NF] = {};
    bf16x8 afl[4][2], afh[4][2], bfl[NH2][2], bfh[NH2][2];

    const int NT    = K >> 6;                    // K % 128 == 0 -> NT even
    const int niter = NT >> 1;

    // prologue: stage tiles 0 and 1 fully; wait tile0 landed (tile1 in flight);
    // then issue the ph3-role reads for tile 0 (afl, bfl).
    ST_A(0, 0, 0); ST_A(0, 0, 64); ST_A(0, 0, 128); ST_A(0, 0, 192);
    ST_B(0, 0, 0); ST_B(0, 0, 64);
    if constexpr (NF == 4) { ST_B(0, 0, 128); ST_B(0, 0, 192); }
    ST_A(BUFSZ, 1, 0); ST_A(BUFSZ, 1, 64); ST_A(BUFSZ, 1, 128); ST_A(BUFSZ, 1, 192);
    ST_B(BUFSZ, 1, 0); ST_B(BUFSZ, 1, 64);
    if constexpr (NF == 4) { ST_B(BUFSZ, 1, 128); ST_B(BUFSZ, 1, 192); }
    asm volatile("s_waitcnt vmcnt(%0)" :: "i"(LPT) : "memory");
    __builtin_amdgcn_s_barrier();
    __builtin_amdgcn_sched_barrier(0);
    RD_AF(afl, 0, 0); RD_BF(bfl, 0, 0);

    for (int it = 0; it < niter; ++it) {
        const int  t    = it << 1;
        const bool more = (it + 1) < niter;
        G_TILE(0,     BUFSZ, t + 2, true, more);  // even tile (buf0), stage t+2
        G_TILE(BUFSZ, 0,     t + 3, more, more);  // odd  tile (buf1), stage t+3
    }

    // epilogue: C/D layout col=lane&15, row=(lane>>4)*4+reg [m89/m91]
    const int cr   = (lane >> 4) << 2;
    const int ccol = lane & 15;
    #pragma unroll
    for (int fr = 0; fr < 8; ++fr) {
        #pragma unroll
        for (int fc = 0; fc < NF; ++fc) {
            const int gc = bn + fc * 64 + wn_idx * 16 + ccol;
            const float bv = BIAS ? bias[gc] : 0.0f;
            #pragma unroll
            for (int j = 0; j < 4; ++j) {
                const int gr = bm + wm_idx * 128 + fr * 16 + cr + j;
                float vv = acc[fr][fc][j] + bv;
                if (ACT == ACT_ELU1) vv = fast_elu1(vv);
                if (ACT == ACT_GELU) vv = fast_gelu(vv);
                if (ACT == ACT_QKV)  vv = (bn < 2048) ? fast_elu1(vv) : vv;
                const size_t oidx = (size_t)gr * N + gc;
                if (RES) vv += resid[oidx];
                if (OUTF32) ((float*)Cout)[oidx] = vv;
                else        ((ushort_t*)Cout)[oidx] = f2b(vv);
            }
        }
    }
    (void)M;
}

// ---------------------------------------------------------------- attention
// qkv buffer row stride = QSTR; K at col 1024, V at col 2048
__global__ void __launch_bounds__(256)
attn_phase1(const ushort_t* __restrict__ qkv,
            float* __restrict__ P, float* __restrict__ Ksum)
{
    const int c = blockIdx.x, h = blockIdx.y, b = blockIdx.z;
    __shared__ ushort_t Ks[64][68], Vs[64][68];
    const int tid = threadIdx.x;
    const size_t rowbase = (size_t)b * SEQ + c * 64;
    #pragma unroll
    for (int i = 0; i < 4; i++) {
        const int lin = tid + 256 * i;          // (t, d4) over 64x16
        const int t = lin >> 4, d4 = (lin & 15) * 4;
        const size_t gidx = (rowbase + t) * QSTR + h * HD + d4;
        *(uint2*)&Ks[t][d4] = *(const uint2*)(qkv + 1024 + gidx);
        *(uint2*)&Vs[t][d4] = *(const uint2*)(qkv + 2048 + gidx);
    }
    __syncthreads();
    const int d0 = (tid >> 4) * 4, e0 = (tid & 15) * 4;
    float acc[4][4] = {};
    for (int t = 0; t < 64; t++) {
        float kf[4], vf[4];
        unpack4(*(const uint2*)&Ks[t][d0], kf);
        unpack4(*(const uint2*)&Vs[t][e0], vf);
        #pragma unroll
        for (int i = 0; i < 4; i++)
            #pragma unroll
            for (int j = 0; j < 4; j++)
                acc[i][j] += kf[i] * vf[j];
    }
    const size_t pbase = (((size_t)b * NH + h) * NCHUNK + c) * 4096;
    #pragma unroll
    for (int i = 0; i < 4; i++) {
        float4 o; o.x = acc[i][0]; o.y = acc[i][1]; o.z = acc[i][2]; o.w = acc[i][3];
        *(float4*)(P + pbase + (size_t)(d0 + i) * 64 + e0) = o;
    }
    if (tid < 64) {
        float a = 0.0f;
        for (int t = 0; t < 64; t++) a += b2f(Ks[t][tid]);
        Ksum[(((size_t)b * NH + h) * NCHUNK + c) * 64 + tid] = a;
    }
}

// phase 1b: exclusive prefix over chunks, column-parallel.
__global__ void __launch_bounds__(256)
attn_prefix(float* __restrict__ P, float* __restrict__ Ksum)
{
    const int bh = blockIdx.y;
    const int e  = blockIdx.x * 256 + threadIdx.x;
    const size_t base = (size_t)bh * NCHUNK * 4096 + e;
    float acc = 0.0f;
    #pragma unroll
    for (int c = 0; c < NCHUNK; c++) {
        const float t = P[base + (size_t)c * 4096];
        P[base + (size_t)c * 4096] = acc;
        acc += t;
    }
    if (blockIdx.x == 0 && threadIdx.x < 64) {
        const size_t kb = (size_t)bh * NCHUNK * 64 + threadIdx.x;
        float a = 0.0f;
        #pragma unroll
        for (int c = 0; c < NCHUNK; c++) {
            const float t = Ksum[kb + c * 64];
            Ksum[kb + c * 64] = a;
            a += t;
        }
    }
}

// phase 2: out = (Q@M_prev + causal(QK^T)@V) / (Q@ksum_prev + rowsum(S) + 1e-6)
__global__ void __launch_bounds__(256)
attn_phase2(const ushort_t* __restrict__ qkv, const float* __restrict__ P,
            const float* __restrict__ Ksum, ushort_t* __restrict__ Out)
{
    const int c = blockIdx.x, h = blockIdx.y, b = blockIdx.z;
    const int tid = threadIdx.x;
    __shared__ ushort_t Qs[64][68], KsB[64][68], VsB[64][68];
    __shared__ float S[64][68];
    __shared__ float Mp[64][64];
    __shared__ float kp[64];
    __shared__ float partial[4][64];
    const size_t rowbase = (size_t)b * SEQ + c * 64;
    const size_t pbase = (((size_t)b * NH + h) * NCHUNK + c) * 4096;
    #pragma unroll
    for (int i = 0; i < 4; i++) {
        const int lin = tid + 256 * i;          // (t, d4) over 64x16
        const int t = lin >> 4, d4 = (lin & 15) * 4;
        const size_t gidx = (rowbase + t) * QSTR + h * HD + d4;
        *(uint2*)&Qs[t][d4]  = *(const uint2*)(qkv + gidx);
        *(uint2*)&KsB[t][d4] = *(const uint2*)(qkv + 1024 + gidx);
        *(uint2*)&VsB[t][d4] = *(const uint2*)(qkv + 2048 + gidx);
        *(float4*)&Mp[t][d4] = *(const float4*)(P + pbase + lin * 4);
    }
    if (tid < 64) kp[tid] = Ksum[(((size_t)b * NH + h) * NCHUNK + c) * 64 + tid];
    __syncthreads();

    const int t0 = (tid >> 4) * 4;
    const int c0 = (tid & 15) * 4;              // ii-block for S phase, e-block later

    // S = causal(Q K^T); masked entries written as 0
    {
        float accS[4][4] = {};
        for (int d4 = 0; d4 < 64; d4 += 4) {
            float qf[4][4], kf[4][4];
            #pragma unroll
            for (int i = 0; i < 4; i++) {
                unpack4(*(const uint2*)&Qs[t0 + i][d4], qf[i]);
                unpack4(*(const uint2*)&KsB[c0 + i][d4], kf[i]);
            }
            #pragma unroll
            for (int i = 0; i < 4; i++)
                #pragma unroll
                for (int j = 0; j < 4; j++)
                    #pragma unroll
                    for (int dd = 0; dd < 4; dd++)
                        accS[i][j] += qf[i][dd] * kf[j][dd];
        }
        #pragma unroll
        for (int i = 0; i < 4; i++) {
            float4 sv;
            sv.x = (c0 + 0 <= t0 + i) ? accS[i][0] : 0.0f;
            sv.y = (c0 + 1 <= t0 + i) ? accS[i][1] : 0.0f;
            sv.z = (c0 + 2 <= t0 + i) ? accS[i][2] : 0.0f;
            sv.w = (c0 + 3 <= t0 + i) ? accS[i][3] : 0.0f;
            *(float4*)&S[t0 + i][c0] = sv;
        }
    }
    __syncthreads();

    // den partials: quarter-range per thread
    {
        const int t = tid & 63, q = tid >> 6;
        const int base = q * 16;
        float a = 0.0f;
        #pragma unroll
        for (int ii = 0; ii < 16; ii++) a += S[t][base + ii];
        #pragma unroll
        for (int d = 0; d < 16; d++) a += b2f(Qs[t][base + d]) * kp[base + d];
        partial[q][t] = a;
    }
    __syncthreads();

    // out = S@V + Q@Mp, then /den
    float acc[4][4] = {};
    for (int ii = 0; ii < 64; ii++) {
        float vf[4];
        unpack4(*(const uint2*)&VsB[ii][c0], vf);
        #pragma unroll
        for (int i = 0; i < 4; i++) {
            const float s = S[t0 + i][ii];
            #pragma unroll
            for (int j = 0; j < 4; j++) acc[i][j] += s * vf[j];
        }
    }
    for (int d = 0; d < 64; d++) {
        const float4 mp = *(const float4*)&Mp[d][c0];
        #pragma unroll
        for (int i = 0; i < 4; i++) {
            const float qv = b2f(Qs[t0 + i][d]);
            acc[i][0] += qv * mp.x; acc[i][1] += qv * mp.y;
            acc[i][2] += qv * mp.z; acc[i][3] += qv * mp.w;
        }
    }
    #pragma unroll
    for (int i = 0; i < 4; i++) {
        const float dent = partial[0][t0 + i] + partial[1][t0 + i] +
                           partial[2][t0 + i] + partial[3][t0 + i] + 1e-6f;
        const float r = 1.0f / dent;
        ushort_t o[4];
        #pragma unroll
        for (int j = 0; j < 4; j++) o[j] = f2b(acc[i][j] * r);
        uint2 u2;
        u2.x = (unsigned int)o[0] | ((unsigned int)o[1] << 16);
        u2.y = (unsigned int)o[2] | ((unsigned int)o[3] << 16);
        *(uint2*)(Out + (rowbase + t0 + i) * DIM + h * HD + c0) = u2;
    }
}

// ---------------------------------------------------------------- launcher
extern "C" void kernel_launch(void* const* d_in, const int* in_sizes, int n_in,
                              void* d_out, int out_size, void* d_ws, size_t ws_size,
                              hipStream_t stream)
{
    const float* x      = (const float*)d_in[0];
    const float* Wq     = (const float*)d_in[1];
    const float* Wk     = (const float*)d_in[2];
    const float* Wv     = (const float*)d_in[3];
    const float* Wo     = (const float*)d_in[4];
    const float* ln1g   = (const float*)d_in[5];
    const float* ln1b   = (const float*)d_in[6];
    const float* ln2g   = (const float*)d_in[7];
    const float* ln2b   = (const float*)d_in[8];
    const float* cw1    = (const float*)d_in[9];
    const float* cb1    = (const float*)d_in[10];
    const float* cw2    = (const float*)d_in[11];
    const float* cb2    = (const float*)d_in[12];

    char* ws = (char*)d_ws;
    ushort_t* h     = (ushort_t*)(ws + OFF_H);
    ushort_t* qkv   = (ushort_t*)(ws + OFF_Q);
    float*    Pb    = (float*)(ws + OFF_P);
    float*    ksb   = (float*)(ws + OFF_KS);
    float*    x1    = (float*)(ws + OFF_X1);
    ushort_t* wqkvt = (ushort_t*)(ws + OFF_WQT);
    ushort_t* wot   = (ushort_t*)(ws + OFF_WOT);
    ushort_t* w1t   = (ushort_t*)(ws + OFF_W1T);
    ushort_t* w2t   = (ushort_t*)(ws + OFF_W2T);
    ushort_t* hid   = (ushort_t*)(ws + OFF_HIDB);
    float*    outp  = (float*)d_out;

    const dim3 tb(32, 8);
    // fused qkv weight^T: [3072][1024]
    transpose_f32_bf16<<<dim3(32, 32), tb, 0, stream>>>(Wq, wqkvt,                   DIM, DIM);
    transpose_f32_bf16<<<dim3(32, 32), tb, 0, stream>>>(Wk, wqkvt + 1024 * 1024,     DIM, DIM);
    transpose_f32_bf16<<<dim3(32, 32), tb, 0, stream>>>(Wv, wqkvt + 2 * 1024 * 1024, DIM, DIM);
    transpose_f32_bf16<<<dim3(32, 32), tb, 0, stream>>>(Wo, wot, DIM, DIM);
    for (int l = 0; l < 3; l++) {
        transpose_f32_bf16<<<dim3(128, 32), tb, 0, stream>>>(cw1 + (size_t)l * DIM * HID,
                                                             w1t + (size_t)l * HID * DIM, DIM, HID);
        transpose_f32_bf16<<<dim3(32, 128), tb, 0, stream>>>(cw2 + (size_t)l * HID * DIM,
                                                             w2t + (size_t)l * DIM * HID, HID, DIM);
    }

    ln_fwd<<<MROWS, 256, 0, stream>>>(x, ln1g, ln1b, h);

    // fused Q|K|V projection: [8192][3072], BN=128 -> 32x24 = 768 wg
    gemm256<128, ACT_QKV, false, false, false><<<dim3(32, 24), 512, 0, stream>>>(
        h, wqkvt, nullptr, nullptr, qkv, MROWS, QSTR, DIM);

    attn_phase1<<<dim3(NCHUNK, NH, NB), 256, 0, stream>>>(qkv, Pb, ksb);
    attn_prefix<<<dim3(16, 64), 256, 0, stream>>>(Pb, ksb);
    attn_phase2<<<dim3(NCHUNK, NH, NB), 256, 0, stream>>>(qkv, Pb, ksb, h);  // h := attn out

    // Wo: N=1024, BN=128 -> 32x8 = 256 wg (exact fill)
    gemm256<128, ACT_NONE, false, true, true><<<dim3(32, 8), 512, 0, stream>>>(
        h, wot, nullptr, x, x1, MROWS, DIM, DIM);

    ln_fwd<<<MROWS, 256, 0, stream>>>(x1, ln2g, ln2b, h);

    const ushort_t* cur = h;
    for (int l = 0; l < 3; l++) {
        // w1: N=4096, BN=128 -> 32x32 = 1024 wg = 4 full waves
        gemm256<128, ACT_GELU, true, false, false><<<dim3(32, 32), 512, 0, stream>>>(
            cur, w1t + (size_t)l * HID * DIM, cb1 + (size_t)l * HID, nullptr, hid, MROWS, HID, DIM);
        if (l < 2) {
            // w2: N=1024 K=4096, BN=128 -> 256 wg (exact fill)
            gemm256<128, ACT_NONE, true, false, false><<<dim3(32, 8), 512, 0, stream>>>(
                hid, w2t + (size_t)l * DIM * HID, cb2 + (size_t)l * DIM, nullptr, h, MROWS, DIM, HID);
            cur = h;
        } else {
            gemm256<128, ACT_NONE, true, true, true><<<dim3(32, 8), 512, 0, stream>>>(
                hid, w2t + (size_t)l * DIM * HID, cb2 + (size_t)l * DIM, x1, outp, MROWS, DIM, HID);
        }
    }
    (void)in_sizes; (void)n_in; (void)out_size; (void)ws_size;
}